// Round 1
// baseline (6350.903 us; speedup 1.0000x reference)
//
#include <hip/hip_runtime.h>
#include <hip/hip_bf16.h>

#define BS 64
#define SEQ 200
#define NSK 4096
#define DS 256
#define SM 64
#define NROWS (BS*SEQ)

__device__ __forceinline__ float sigf(float x){ return 1.0f/(1.0f+expf(-x)); }

// ---------------- Kernel A: gather k,v + attention softmax w ----------------
// 1 wave per (b,s) row; 4 rows per block.
__global__ __launch_bounds__(256) void k_gather_attn(
    const int* __restrict__ q, const int* __restrict__ r,
    const float* __restrict__ k_emb, const float* __restrict__ x_emb,
    const float* __restrict__ Mk,
    float* __restrict__ X2, float* __restrict__ vbuf, float* __restrict__ wbuf)
{
  __shared__ float ks[4][DS];
  const int tid = threadIdx.x;
  const int wv = tid >> 6, ln = tid & 63;
  const int row = blockIdx.x * 4 + wv;
  const int b = row / SEQ, s = row % SEQ;
  const int qi = q[b*SEQ + s];
  const int ri = r[b*SEQ + s];
  const float4* kr = (const float4*)(k_emb + (size_t)qi * DS);
  const float4* vr = (const float4*)(x_emb + ((size_t)qi + (size_t)NSK * ri) * DS);
  float4 kv = kr[ln];
  float4 vv = vr[ln];
  // X2 row layout: [reads(256) | k(256)]
  ((float4*)(X2 + (size_t)row*512 + DS))[ln] = kv;
  ((float4*)(vbuf + (size_t)row*DS))[ln] = vv;
  *((float4*)&ks[wv][ln*4]) = kv;
  __syncthreads();
  // logit for memory slot m = ln
  const float4* mkr = (const float4*)(Mk + (size_t)ln * DS);
  float a0=0.f,a1=0.f,a2=0.f,a3=0.f;
  #pragma unroll 8
  for (int d4=0; d4<DS/4; d4++){
    float4 m4 = mkr[d4];
    float4 k4 = *((const float4*)&ks[wv][d4*4]);
    a0 += m4.x*k4.x; a1 += m4.y*k4.y; a2 += m4.z*k4.z; a3 += m4.w*k4.w;
  }
  float lg = (a0+a1)+(a2+a3);
  float mx = lg;
  #pragma unroll
  for (int off=32; off; off>>=1) mx = fmaxf(mx, __shfl_xor(mx, off));
  float ex = expf(lg - mx);
  float sm = ex;
  #pragma unroll
  for (int off=32; off; off>>=1) sm += __shfl_xor(sm, off);
  wbuf[(size_t)row*SM + ln] = ex / sm;
}

// ---------------- Generic tiled f32 GEMM: C = act(A @ W^T + bias) ----------
// A may be split in K: first K0 cols from A0 (leading dim lda0), next K1 from A1.
// W is row-major (N, K0+K1). Tiles 64x64x16, 256 threads, 4x4 per thread.
template<int ACT>  // 0 none, 1 sigmoid, 2 tanh
__global__ __launch_bounds__(256) void k_gemm(
    const float* __restrict__ A0, int lda0, int K0,
    const float* __restrict__ A1, int lda1, int K1,
    const float* __restrict__ W, const float* __restrict__ bias,
    float* __restrict__ C, int N)
{
  const int K = K0 + K1;
  __shared__ float As[16][68];
  __shared__ float Bs[16][68];
  const int tid = threadIdx.x;
  const int m0 = blockIdx.x * 64, n0 = blockIdx.y * 64;
  const int lr = tid >> 2;          // 0..63
  const int lk = (tid & 3) * 4;     // 0,4,8,12
  const int ty = tid >> 4, tx = tid & 15;
  float acc[4][4] = {{0.f}};
  for (int k0=0; k0<K; k0+=16){
    float4 av;
    if (k0 + lk < K0)   // K0 is a multiple of 16, so branch is tile-uniform
      av = *(const float4*)(A0 + (size_t)(m0+lr)*lda0 + (k0 + lk));
    else
      av = *(const float4*)(A1 + (size_t)(m0+lr)*lda1 + (k0 + lk - K0));
    float4 wv = *(const float4*)(W + (size_t)(n0+lr)*K + (k0 + lk));
    As[lk+0][lr]=av.x; As[lk+1][lr]=av.y; As[lk+2][lr]=av.z; As[lk+3][lr]=av.w;
    Bs[lk+0][lr]=wv.x; Bs[lk+1][lr]=wv.y; Bs[lk+2][lr]=wv.z; Bs[lk+3][lr]=wv.w;
    __syncthreads();
    #pragma unroll
    for (int kk=0; kk<16; kk++){
      float a[4], bb[4];
      #pragma unroll
      for (int i=0;i<4;i++) a[i]  = As[kk][ty*4+i];
      #pragma unroll
      for (int j=0;j<4;j++) bb[j] = Bs[kk][tx*4+j];
      #pragma unroll
      for (int i=0;i<4;i++)
        #pragma unroll
        for (int j=0;j<4;j++)
          acc[i][j] += a[i]*bb[j];
    }
    __syncthreads();
  }
  #pragma unroll
  for (int i=0;i<4;i++){
    #pragma unroll
    for (int j=0;j<4;j++){
      int n = n0 + tx*4 + j;
      float v = acc[i][j] + bias[n];
      if (ACT==1) v = sigf(v);
      else if (ACT==2) v = tanhf(v);
      C[(size_t)(m0+ty*4+i)*N + n] = v;
    }
  }
}

// ---------------- Memory scan (sequential over t) ---------------------------
// 1 block per batch; thread d owns memory column d (64 slots in registers).
__global__ __launch_bounds__(256) void k_scan(
    const float* __restrict__ wbuf, const float* __restrict__ ebuf,
    const float* __restrict__ abuf, const float* __restrict__ Mv0,
    float* __restrict__ X2)
{
  const int b = blockIdx.x;
  const int d = threadIdx.x;
  __shared__ float ws[SM];
  float mem[SM];
  #pragma unroll
  for (int m=0;m<SM;m++) mem[m] = Mv0[m*DS + d];
  for (int t=0;t<SEQ;t++){
    const size_t row = (size_t)b*SEQ + t;
    if (d < SM) ws[d] = wbuf[row*SM + d];
    const float e = ebuf[row*DS + d];
    const float a = abuf[row*DS + d];
    __syncthreads();
    float r0=0.f,r1=0.f,r2=0.f,r3=0.f;
    #pragma unroll
    for (int m=0;m<SM;m+=4){
      float w0=ws[m], w1=ws[m+1], w2=ws[m+2], w3=ws[m+3];
      r0 += w0*mem[m];   mem[m]   += w0*fmaf(-e, mem[m],   a);
      r1 += w1*mem[m+1]; mem[m+1] += w1*fmaf(-e, mem[m+1], a);
      r2 += w2*mem[m+2]; mem[m+2] += w2*fmaf(-e, mem[m+2], a);
      r3 += w3*mem[m+3]; mem[m+3] += w3*fmaf(-e, mem[m+3], a);
    }
    X2[row*512 + d] = (r0+r1)+(r2+r3);   // reads part of X2 row
    __syncthreads();
  }
}

// ---------------- LSTM (sequential over t) ----------------------------------
// 1 block per batch, 1024 threads = 1 per gate. p output fused.
__global__ __launch_bounds__(1024) void k_lstm(
    const float* __restrict__ gin, const float* __restrict__ W_hh,
    const float* __restrict__ b_hh, const float* __restrict__ hx,
    const float* __restrict__ cx, const float* __restrict__ W_p,
    const float* __restrict__ b_p, float* __restrict__ out)
{
  const int b = blockIdx.x;
  const int tid = threadIdx.x;
  __shared__ float hsm[DS];
  __shared__ float gl[4*DS];
  __shared__ float red[4];
  float c_ = 0.f, wp = 0.f;
  if (tid < DS){ hsm[tid] = hx[tid]; c_ = cx[tid]; wp = W_p[tid]; }
  const float bh = b_hh[tid];
  const float4* wr4 = (const float4*)(W_hh + (size_t)tid * DS);
  __syncthreads();
  for (int t=0;t<SEQ;t++){
    const size_t row = (size_t)b*SEQ + t;
    float a0=0.f,a1=0.f,a2=0.f,a3=0.f;
    #pragma unroll 8
    for (int d4=0; d4<DS/4; d4++){
      float4 w4 = wr4[d4];
      float4 h4 = *((const float4*)&hsm[d4*4]);
      a0 += w4.x*h4.x; a1 += w4.y*h4.y; a2 += w4.z*h4.z; a3 += w4.w*h4.w;
    }
    gl[tid] = gin[row*1024 + tid] + bh + ((a0+a1)+(a2+a3));
    __syncthreads();
    if (tid < DS){
      float ig = sigf(gl[tid]);
      float fg = sigf(gl[DS+tid]);
      float gg = tanhf(gl[2*DS+tid]);
      float og = sigf(gl[3*DS+tid]);
      c_ = fg*c_ + ig*gg;
      float h = og*tanhf(c_);
      hsm[tid] = h;
      float pp = h*wp;
      #pragma unroll
      for (int off=32; off; off>>=1) pp += __shfl_xor(pp, off);
      if ((tid&63)==0) red[tid>>6] = pp;
    }
    __syncthreads();
    if (tid == 0) out[row] = sigf(red[0]+red[1]+red[2]+red[3] + b_p[0]);
  }
}

extern "C" void kernel_launch(void* const* d_in, const int* in_sizes, int n_in,
                              void* d_out, int out_size, void* d_ws, size_t ws_size,
                              hipStream_t stream)
{
  const int*   q     = (const int*)d_in[0];
  const int*   r     = (const int*)d_in[1];
  const float* k_emb = (const float*)d_in[2];
  const float* x_emb = (const float*)d_in[3];
  const float* Mk    = (const float*)d_in[4];
  const float* Mv0   = (const float*)d_in[5];
  const float* W_a   = (const float*)d_in[6];
  const float* b_a   = (const float*)d_in[7];
  const float* W_e   = (const float*)d_in[8];
  const float* b_e   = (const float*)d_in[9];
  const float* W_add = (const float*)d_in[10];
  const float* b_add = (const float*)d_in[11];
  const float* W_f   = (const float*)d_in[12];
  const float* b_f   = (const float*)d_in[13];
  const float* hx    = (const float*)d_in[14];
  const float* cx    = (const float*)d_in[15];
  const float* W_ih  = (const float*)d_in[16];
  const float* b_ih  = (const float*)d_in[17];
  const float* W_hh  = (const float*)d_in[18];
  const float* b_hh  = (const float*)d_in[19];
  const float* W_p   = (const float*)d_in[20];
  const float* b_p   = (const float*)d_in[21];
  float* out = (float*)d_out;

  // workspace layout (floats). gin overlays [vbuf|webuf|ebuf|abuf] (dead by then).
  float* ws    = (float*)d_ws;
  float* vbuf  = ws;                              // 12800*256
  float* webuf = vbuf  + (size_t)NROWS*DS;        // 12800*256
  float* ebuf  = webuf + (size_t)NROWS*DS;        // 12800*256
  float* abuf  = ebuf  + (size_t)NROWS*DS;        // 12800*256
  float* gin   = vbuf;                            // 12800*1024 (overlay)
  float* X2    = abuf  + (size_t)NROWS*DS;        // 12800*512  [reads|k]
  float* wbuf  = X2    + (size_t)NROWS*512;       // 12800*64
  float* fbuf  = wbuf  + (size_t)NROWS*SM;        // 12800*256
  // total = 95.0 MB

  k_gather_attn<<<NROWS/4, 256, 0, stream>>>(q, r, k_emb, x_emb, Mk, X2, vbuf, wbuf);
  // we = [k|v] @ W_a^T + b_a
  k_gemm<0><<<dim3(NROWS/64, 4), 256, 0, stream>>>(X2+DS, 512, DS, vbuf, DS, DS, W_a, b_a, webuf, DS);
  // erase = sigmoid(we @ W_e^T + b_e), add = tanh(we @ W_add^T + b_add)
  k_gemm<1><<<dim3(NROWS/64, 4), 256, 0, stream>>>(webuf, DS, DS, nullptr, 0, 0, W_e,   b_e,   ebuf, DS);
  k_gemm<2><<<dim3(NROWS/64, 4), 256, 0, stream>>>(webuf, DS, DS, nullptr, 0, 0, W_add, b_add, abuf, DS);
  // sequential memory scan -> reads into X2[:,0:256]
  k_scan<<<BS, DS, 0, stream>>>(wbuf, ebuf, abuf, Mv0, X2);
  // f = tanh([reads|k] @ W_f^T + b_f)
  k_gemm<2><<<dim3(NROWS/64, 4), 256, 0, stream>>>(X2, 512, DS, X2+DS, 512, DS, W_f, b_f, fbuf, DS);
  // gin = f @ W_ih^T + b_ih   (b_hh added inside LSTM)
  k_gemm<0><<<dim3(NROWS/64, 16), 256, 0, stream>>>(fbuf, DS, DS, nullptr, 0, 0, W_ih, b_ih, gin, 1024);
  // LSTM + p output
  k_lstm<<<BS, 1024, 0, stream>>>(gin, W_hh, b_hh, hx, cx, W_p, b_p, out);
}

// Round 2
// 1903.909 us; speedup vs baseline: 3.3357x; 3.3357x over previous
//
#include <hip/hip_runtime.h>
#include <hip/hip_bf16.h>

#define BS 64
#define SEQ 200
#define NSK 4096
#define DS 256
#define SM 64
#define NROWS (BS*SEQ)
#define NBLK 4

typedef __attribute__((ext_vector_type(8))) short bf16x8;
typedef __attribute__((ext_vector_type(4))) float f32x4;

__device__ __forceinline__ float sigf(float x){ return 1.0f/(1.0f+expf(-x)); }
__device__ __forceinline__ float fast_sig(float x){ return 1.0f/(1.0f+__expf(-x)); }
__device__ __forceinline__ float fast_tanh(float x){
  float t = __expf(-2.0f*fabsf(x));
  float r = (1.0f - t)/(1.0f + t);
  return copysignf(r, x);
}
// f32 -> bf16 round-to-nearest-even
__device__ __forceinline__ short f2bf(float x){
  unsigned int u = __float_as_uint(x);
  unsigned int r = (u + 0x7fffu + ((u >> 16) & 1u)) >> 16;
  return (short)r;
}
__device__ __forceinline__ float bf2f(unsigned short s){
  return __uint_as_float(((unsigned int)s) << 16);
}

// ---------------- Kernel A: gather k,v + attention softmax w ----------------
__global__ __launch_bounds__(256) void k_gather_attn(
    const int* __restrict__ q, const int* __restrict__ r,
    const float* __restrict__ k_emb, const float* __restrict__ x_emb,
    const float* __restrict__ Mk,
    float* __restrict__ X2, float* __restrict__ vbuf, float* __restrict__ wbuf)
{
  __shared__ float ks[4][DS];
  const int tid = threadIdx.x;
  const int wv = tid >> 6, ln = tid & 63;
  const int row = blockIdx.x * 4 + wv;
  const int b = row / SEQ, s = row % SEQ;
  const int qi = q[b*SEQ + s];
  const int ri = r[b*SEQ + s];
  const float4* kr = (const float4*)(k_emb + (size_t)qi * DS);
  const float4* vr = (const float4*)(x_emb + ((size_t)qi + (size_t)NSK * ri) * DS);
  float4 kv = kr[ln];
  float4 vv = vr[ln];
  ((float4*)(X2 + (size_t)row*512 + DS))[ln] = kv;
  ((float4*)(vbuf + (size_t)row*DS))[ln] = vv;
  *((float4*)&ks[wv][ln*4]) = kv;
  __syncthreads();
  const float4* mkr = (const float4*)(Mk + (size_t)ln * DS);
  float a0=0.f,a1=0.f,a2=0.f,a3=0.f;
  #pragma unroll 8
  for (int d4=0; d4<DS/4; d4++){
    float4 m4 = mkr[d4];
    float4 k4 = *((const float4*)&ks[wv][d4*4]);
    a0 += m4.x*k4.x; a1 += m4.y*k4.y; a2 += m4.z*k4.z; a3 += m4.w*k4.w;
  }
  float lg = (a0+a1)+(a2+a3);
  float mx = lg;
  #pragma unroll
  for (int off=32; off; off>>=1) mx = fmaxf(mx, __shfl_xor(mx, off));
  float ex = expf(lg - mx);
  float sm = ex;
  #pragma unroll
  for (int off=32; off; off>>=1) sm += __shfl_xor(sm, off);
  wbuf[(size_t)row*SM + ln] = ex / sm;
}

// ---------------- Generic tiled f32 GEMM: C = act(A @ W^T + bias [+bias2]) --
template<int ACT>  // 0 none, 1 sigmoid, 2 tanh
__global__ __launch_bounds__(256) void k_gemm(
    const float* __restrict__ A0, int lda0, int K0,
    const float* __restrict__ A1, int lda1, int K1,
    const float* __restrict__ W, const float* __restrict__ bias,
    const float* __restrict__ bias2,
    float* __restrict__ C, int N)
{
  const int K = K0 + K1;
  __shared__ float As[16][68];
  __shared__ float Bs[16][68];
  const int tid = threadIdx.x;
  const int m0 = blockIdx.x * 64, n0 = blockIdx.y * 64;
  const int lr = tid >> 2;
  const int lk = (tid & 3) * 4;
  const int ty = tid >> 4, tx = tid & 15;
  float acc[4][4] = {{0.f}};
  for (int k0=0; k0<K; k0+=16){
    float4 av;
    if (k0 + lk < K0)
      av = *(const float4*)(A0 + (size_t)(m0+lr)*lda0 + (k0 + lk));
    else
      av = *(const float4*)(A1 + (size_t)(m0+lr)*lda1 + (k0 + lk - K0));
    float4 wv = *(const float4*)(W + (size_t)(n0+lr)*K + (k0 + lk));
    As[lk+0][lr]=av.x; As[lk+1][lr]=av.y; As[lk+2][lr]=av.z; As[lk+3][lr]=av.w;
    Bs[lk+0][lr]=wv.x; Bs[lk+1][lr]=wv.y; Bs[lk+2][lr]=wv.z; Bs[lk+3][lr]=wv.w;
    __syncthreads();
    #pragma unroll
    for (int kk=0; kk<16; kk++){
      float a[4], bb[4];
      #pragma unroll
      for (int i=0;i<4;i++) a[i]  = As[kk][ty*4+i];
      #pragma unroll
      for (int j=0;j<4;j++) bb[j] = Bs[kk][tx*4+j];
      #pragma unroll
      for (int i=0;i<4;i++)
        #pragma unroll
        for (int j=0;j<4;j++)
          acc[i][j] += a[i]*bb[j];
    }
    __syncthreads();
  }
  #pragma unroll
  for (int i=0;i<4;i++){
    #pragma unroll
    for (int j=0;j<4;j++){
      int n = n0 + tx*4 + j;
      float v = acc[i][j] + bias[n];
      if (bias2) v += bias2[n];
      if (ACT==1) v = sigf(v);
      else if (ACT==2) v = tanhf(v);
      C[(size_t)(m0+ty*4+i)*N + n] = v;
    }
  }
}

// ---------------- Memory scan (sequential over t) ---------------------------
__global__ __launch_bounds__(256) void k_scan(
    const float* __restrict__ wbuf, const float* __restrict__ ebuf,
    const float* __restrict__ abuf, const float* __restrict__ Mv0,
    float* __restrict__ X2)
{
  const int b = blockIdx.x;
  const int d = threadIdx.x;
  __shared__ float ws[SM];
  float mem[SM];
  #pragma unroll
  for (int m=0;m<SM;m++) mem[m] = Mv0[m*DS + d];
  for (int t=0;t<SEQ;t++){
    const size_t row = (size_t)b*SEQ + t;
    if (d < SM) ws[d] = wbuf[row*SM + d];
    const float e = ebuf[row*DS + d];
    const float a = abuf[row*DS + d];
    __syncthreads();
    float r0=0.f,r1=0.f,r2=0.f,r3=0.f;
    #pragma unroll
    for (int m=0;m<SM;m+=4){
      float w0=ws[m], w1=ws[m+1], w2=ws[m+2], w3=ws[m+3];
      r0 += w0*mem[m];   mem[m]   += w0*fmaf(-e, mem[m],   a);
      r1 += w1*mem[m+1]; mem[m+1] += w1*fmaf(-e, mem[m+1], a);
      r2 += w2*mem[m+2]; mem[m+2] += w2*fmaf(-e, mem[m+2], a);
      r3 += w3*mem[m+3]; mem[m+3] += w3*fmaf(-e, mem[m+3], a);
    }
    X2[row*512 + d] = (r0+r1)+(r2+r3);
    __syncthreads();
  }
}

// ---------------- Cooperative MFMA LSTM -------------------------------------
// 4 blocks x 512 threads (8 waves). Block bb owns global dims [bb*64, bb*64+64).
// Wave (mgrp = wid>>2, ngrp = wid&3): batches [mgrp*32,+32), dims [ngrp*16,+16).
// W_hh rows for all 4 gate types of those dims live in registers as bf16
// B-fragments (loaded once). Per step: stage h(t-1) to swizzled LDS, MFMA,
// in-lane gate fusion (i/f/g/o share lane+reg), write h(t) bf16 to hhist,
// grid barrier.
__global__ __launch_bounds__(512, 2) void k_lstm_coop(
    const float* __restrict__ gin, const float* __restrict__ W_hh,
    const float* __restrict__ hx, const float* __restrict__ cx,
    short* __restrict__ hhist, int* __restrict__ cnt)
{
  const int bb  = blockIdx.x;
  const int tid = threadIdx.x;
  const int l   = tid & 63;
  const int wid = tid >> 6;
  const int ngrp = wid & 3;
  const int mgrp = wid >> 2;

  __shared__ short hsm[64*256];   // 32KB, XOR-swizzled rows of 512B

  // ---- load W_hh slice into registers (bf16 B-fragments), once ----
  // wfr[gt][kt]: lane l holds W[G][k], G = gt*256 + bb*64 + ngrp*16 + (l&15),
  //              k = kt*32 + (l>>4)*8 + j
  bf16x8 wfr[4][8];
  {
    const int col  = l & 15;
    const int krow = (l >> 4) * 8;
    #pragma unroll
    for (int gt=0; gt<4; gt++){
      const int G = gt*256 + bb*64 + ngrp*16 + col;
      const float* wrow = W_hh + (size_t)G*256;
      #pragma unroll
      for (int kt=0; kt<8; kt++){
        const int k0 = kt*32 + krow;
        float4 wa = *(const float4*)(wrow + k0);
        float4 wb = *(const float4*)(wrow + k0 + 4);
        bf16x8 f;
        f[0]=f2bf(wa.x); f[1]=f2bf(wa.y); f[2]=f2bf(wa.z); f[3]=f2bf(wa.w);
        f[4]=f2bf(wb.x); f[5]=f2bf(wb.y); f[6]=f2bf(wb.z); f[7]=f2bf(wb.w);
        wfr[gt][kt] = f;
      }
    }
  }

  // ---- persistent c state: lane owns (b,d) pairs for mt in {0,1}, r in 0..3
  // b = mgrp*32 + mt*16 + (l>>4)*4 + r ; d = ngrp*16 + (l&15)
  const int dloc = ngrp*16 + (l & 15);        // block-local dim 0..63
  const int gdim = bb*64 + dloc;              // global dim
  float c_[8];
  {
    float c0 = cx[gdim];
    #pragma unroll
    for (int p=0;p<8;p++) c_[p] = c0;
  }

  const int srow = tid >> 3;   // 0..63 (staging row = batch)
  const int sseg = tid & 7;    // 64B segment within 512B row

  for (int t=0; t<SEQ; t++){
    // ---- stage h(t-1) into swizzled LDS ----
    if (t == 0){
      #pragma unroll
      for (int u=0; u<4; u++){
        const int kbyte = sseg*64 + u*16;
        const int d0 = kbyte >> 1;
        float4 ha = *(const float4*)(hx + d0);
        float4 hb = *(const float4*)(hx + d0 + 4);
        bf16x8 v;
        v[0]=f2bf(ha.x); v[1]=f2bf(ha.y); v[2]=f2bf(ha.z); v[3]=f2bf(ha.w);
        v[4]=f2bf(hb.x); v[5]=f2bf(hb.y); v[6]=f2bf(hb.z); v[7]=f2bf(hb.w);
        *(bf16x8*)((char*)hsm + srow*512 + (kbyte ^ ((srow&7)<<4))) = v;
      }
    } else {
      const short* src = hhist + ((size_t)(srow*SEQ + (t-1)))*256;
      #pragma unroll
      for (int u=0; u<4; u++){
        const int kbyte = sseg*64 + u*16;
        bf16x8 v = *(const bf16x8*)((const char*)src + kbyte);
        *(bf16x8*)((char*)hsm + srow*512 + (kbyte ^ ((srow&7)<<4))) = v;
      }
    }
    __syncthreads();

    // ---- MFMA: gates for (32 batches x 16 dims x 4 gate types) ----
    f32x4 acc[2][4];
    #pragma unroll
    for (int mt=0; mt<2; mt++)
      #pragma unroll
      for (int gt=0; gt<4; gt++)
        acc[mt][gt] = (f32x4){0.f,0.f,0.f,0.f};

    #pragma unroll
    for (int kt=0; kt<8; kt++){
      const int kbyte = kt*64 + (l>>4)*16;
      const int r0 = mgrp*32 + (l & 15);
      const int r1 = r0 + 16;
      bf16x8 a0 = *(const bf16x8*)((const char*)hsm + r0*512 + (kbyte ^ ((r0&7)<<4)));
      bf16x8 a1 = *(const bf16x8*)((const char*)hsm + r1*512 + (kbyte ^ ((r1&7)<<4)));
      #pragma unroll
      for (int gt=0; gt<4; gt++){
        acc[0][gt] = __builtin_amdgcn_mfma_f32_16x16x32_bf16(a0, wfr[gt][kt], acc[0][gt], 0,0,0);
        acc[1][gt] = __builtin_amdgcn_mfma_f32_16x16x32_bf16(a1, wfr[gt][kt], acc[1][gt], 0,0,0);
      }
    }

    // ---- in-lane gate fusion + c/h update ----
    #pragma unroll
    for (int mt=0; mt<2; mt++){
      const int bbase = mgrp*32 + mt*16 + (l>>4)*4;
      #pragma unroll
      for (int r=0; r<4; r++){
        const int b = bbase + r;
        const float* gr = gin + ((size_t)(b*SEQ + t))*1024 + gdim;
        float iv = gr[0]   + acc[mt][0][r];
        float fv = gr[256] + acc[mt][1][r];
        float gv = gr[512] + acc[mt][2][r];
        float ov = gr[768] + acc[mt][3][r];
        float cc = fast_sig(fv)*c_[mt*4+r] + fast_sig(iv)*fast_tanh(gv);
        c_[mt*4+r] = cc;
        float h = fast_sig(ov)*fast_tanh(cc);
        hhist[((size_t)(b*SEQ + t))*256 + gdim] = f2bf(h);
      }
    }

    // ---- grid barrier (publishes hhist[t] to all blocks) ----
    __syncthreads();
    if (tid == 0){
      __threadfence();
      __hip_atomic_fetch_add(cnt, 1, __ATOMIC_ACQ_REL, __HIP_MEMORY_SCOPE_AGENT);
      while (__hip_atomic_load(cnt, __ATOMIC_ACQUIRE, __HIP_MEMORY_SCOPE_AGENT) < NBLK*(t+1))
        __builtin_amdgcn_s_sleep(1);
      __threadfence();
    }
    __syncthreads();
  }
}

// ---------------- p output: sigmoid(h . W_p + b_p) --------------------------
__global__ __launch_bounds__(256) void k_pout(
    const short* __restrict__ hhist, const float* __restrict__ W_p,
    const float* __restrict__ b_p, float* __restrict__ out)
{
  const int tid = threadIdx.x;
  const int row = blockIdx.x*4 + (tid>>6);
  const int ln = tid & 63;
  ushort4 hv = ((const ushort4*)(hhist + (size_t)row*256))[ln];
  float4 wp = ((const float4*)W_p)[ln];
  float s = bf2f(hv.x)*wp.x + bf2f(hv.y)*wp.y + bf2f(hv.z)*wp.z + bf2f(hv.w)*wp.w;
  #pragma unroll
  for (int off=32; off; off>>=1) s += __shfl_xor(s, off);
  if (ln == 0) out[row] = sigf(s + b_p[0]);
}

extern "C" void kernel_launch(void* const* d_in, const int* in_sizes, int n_in,
                              void* d_out, int out_size, void* d_ws, size_t ws_size,
                              hipStream_t stream)
{
  const int*   q     = (const int*)d_in[0];
  const int*   r     = (const int*)d_in[1];
  const float* k_emb = (const float*)d_in[2];
  const float* x_emb = (const float*)d_in[3];
  const float* Mk    = (const float*)d_in[4];
  const float* Mv0   = (const float*)d_in[5];
  const float* W_a   = (const float*)d_in[6];
  const float* b_a   = (const float*)d_in[7];
  const float* W_e   = (const float*)d_in[8];
  const float* b_e   = (const float*)d_in[9];
  const float* W_add = (const float*)d_in[10];
  const float* b_add = (const float*)d_in[11];
  const float* W_f   = (const float*)d_in[12];
  const float* b_f   = (const float*)d_in[13];
  const float* hx    = (const float*)d_in[14];
  const float* cx    = (const float*)d_in[15];
  const float* W_ih  = (const float*)d_in[16];
  const float* b_ih  = (const float*)d_in[17];
  const float* W_hh  = (const float*)d_in[18];
  const float* b_hh  = (const float*)d_in[19];
  const float* W_p   = (const float*)d_in[20];
  const float* b_p   = (const float*)d_in[21];
  float* out = (float*)d_out;

  // workspace layout (floats):
  float* ws    = (float*)d_ws;
  float* vbuf  = ws;                              // 12800*256
  float* webuf = vbuf  + (size_t)NROWS*DS;
  float* ebuf  = webuf + (size_t)NROWS*DS;
  float* abuf  = ebuf  + (size_t)NROWS*DS;
  float* gin   = vbuf;                            // 12800*1024 overlay (vbuf..abuf)
  float* X2    = abuf  + (size_t)NROWS*DS;        // 12800*512 [reads|k]
  float* wbuf  = X2    + (size_t)NROWS*512;       // 12800*64
  float* fbuf  = wbuf  + (size_t)NROWS*SM;        // 12800*256
  short* hhist = (short*)fbuf;                    // 12800*256 bf16, overlays fbuf (dead)
  int*   cnt   = (int*)wbuf;                      // barrier counter, overlays wbuf (dead)

  k_gather_attn<<<NROWS/4, 256, 0, stream>>>(q, r, k_emb, x_emb, Mk, X2, vbuf, wbuf);
  // we = [k|v] @ W_a^T + b_a
  k_gemm<0><<<dim3(NROWS/64, 4), 256, 0, stream>>>(X2+DS, 512, DS, vbuf, DS, DS, W_a, b_a, nullptr, webuf, DS);
  // erase / add
  k_gemm<1><<<dim3(NROWS/64, 4), 256, 0, stream>>>(webuf, DS, DS, nullptr, 0, 0, W_e,   b_e,   nullptr, ebuf, DS);
  k_gemm<2><<<dim3(NROWS/64, 4), 256, 0, stream>>>(webuf, DS, DS, nullptr, 0, 0, W_add, b_add, nullptr, abuf, DS);
  // memory scan -> reads into X2[:,0:256]
  k_scan<<<BS, DS, 0, stream>>>(wbuf, ebuf, abuf, Mv0, X2);
  // f = tanh([reads|k] @ W_f^T + b_f)
  k_gemm<2><<<dim3(NROWS/64, 4), 256, 0, stream>>>(X2, 512, DS, X2+DS, 512, DS, W_f, b_f, nullptr, fbuf, DS);
  // gin = f @ W_ih^T + (b_ih + b_hh)
  k_gemm<0><<<dim3(NROWS/64, 16), 256, 0, stream>>>(fbuf, DS, DS, nullptr, 0, 0, W_ih, b_ih, b_hh, gin, 1024);
  // cooperative LSTM
  hipMemsetAsync((void*)cnt, 0, sizeof(int), stream);
  {
    const float* gin_c = gin;
    void* args[] = { (void*)&gin_c, (void*)&W_hh, (void*)&hx, (void*)&cx,
                     (void*)&hhist, (void*)&cnt };
    hipLaunchCooperativeKernel((void*)k_lstm_coop, dim3(NBLK), dim3(512), args, 0, stream);
  }
  // p = sigmoid(h . W_p + b_p)
  k_pout<<<NROWS/4, 256, 0, stream>>>(hhist, W_p, b_p, out);
}

// Round 3
// 1415.087 us; speedup vs baseline: 4.4880x; 1.3454x over previous
//
#include <hip/hip_runtime.h>
#include <hip/hip_bf16.h>

#define BS 64
#define SEQ 200
#define NSK 4096
#define DS 256
#define SM 64
#define NROWS (BS*SEQ)
#define LBLK 8   // 4 independent pairs x 2 blocks

typedef __attribute__((ext_vector_type(8))) short bf16x8;
typedef __attribute__((ext_vector_type(4))) float f32x4;

__device__ __forceinline__ float sigf(float x){ return 1.0f/(1.0f+expf(-x)); }
__device__ __forceinline__ float fast_sig(float x){ return 1.0f/(1.0f+__expf(-x)); }
__device__ __forceinline__ float fast_tanh(float x){
  float t = __expf(-2.0f*fabsf(x));
  float r = (1.0f - t)/(1.0f + t);
  return copysignf(r, x);
}
__device__ __forceinline__ short f2bf(float x){
  unsigned int u = __float_as_uint(x);
  unsigned int r = (u + 0x7fffu + ((u >> 16) & 1u)) >> 16;
  return (short)r;
}
__device__ __forceinline__ float bf2f(unsigned short s){
  return __uint_as_float(((unsigned int)s) << 16);
}

// ---------------- Kernel A: gather k,v + attention softmax w ----------------
__global__ __launch_bounds__(256) void k_gather_attn(
    const int* __restrict__ q, const int* __restrict__ r,
    const float* __restrict__ k_emb, const float* __restrict__ x_emb,
    const float* __restrict__ Mk,
    float* __restrict__ X2, float* __restrict__ vbuf, float* __restrict__ wbuf)
{
  __shared__ float ks[4][DS];
  const int tid = threadIdx.x;
  const int wv = tid >> 6, ln = tid & 63;
  const int row = blockIdx.x * 4 + wv;
  const int b = row / SEQ, s = row % SEQ;
  const int qi = q[b*SEQ + s];
  const int ri = r[b*SEQ + s];
  const float4* kr = (const float4*)(k_emb + (size_t)qi * DS);
  const float4* vr = (const float4*)(x_emb + ((size_t)qi + (size_t)NSK * ri) * DS);
  float4 kv = kr[ln];
  float4 vv = vr[ln];
  ((float4*)(X2 + (size_t)row*512 + DS))[ln] = kv;
  ((float4*)(vbuf + (size_t)row*DS))[ln] = vv;
  *((float4*)&ks[wv][ln*4]) = kv;
  __syncthreads();
  const float4* mkr = (const float4*)(Mk + (size_t)ln * DS);
  float a0=0.f,a1=0.f,a2=0.f,a3=0.f;
  #pragma unroll 8
  for (int d4=0; d4<DS/4; d4++){
    float4 m4 = mkr[d4];
    float4 k4 = *((const float4*)&ks[wv][d4*4]);
    a0 += m4.x*k4.x; a1 += m4.y*k4.y; a2 += m4.z*k4.z; a3 += m4.w*k4.w;
  }
  float lg = (a0+a1)+(a2+a3);
  float mx = lg;
  #pragma unroll
  for (int off=32; off; off>>=1) mx = fmaxf(mx, __shfl_xor(mx, off));
  float ex = expf(lg - mx);
  float sm = ex;
  #pragma unroll
  for (int off=32; off; off>>=1) sm += __shfl_xor(sm, off);
  wbuf[(size_t)row*SM + ln] = ex / sm;
}

// ---------------- Generic tiled f32 GEMM: C = act(A @ W^T + bias [+bias2]) --
template<int ACT>
__global__ __launch_bounds__(256) void k_gemm(
    const float* __restrict__ A0, int lda0, int K0,
    const float* __restrict__ A1, int lda1, int K1,
    const float* __restrict__ W, const float* __restrict__ bias,
    const float* __restrict__ bias2,
    float* __restrict__ C, int N)
{
  const int K = K0 + K1;
  __shared__ float As[16][68];
  __shared__ float Bs[16][68];
  const int tid = threadIdx.x;
  const int m0 = blockIdx.x * 64, n0 = blockIdx.y * 64;
  const int lr = tid >> 2;
  const int lk = (tid & 3) * 4;
  const int ty = tid >> 4, tx = tid & 15;
  float acc[4][4] = {{0.f}};
  for (int k0=0; k0<K; k0+=16){
    float4 av;
    if (k0 + lk < K0)
      av = *(const float4*)(A0 + (size_t)(m0+lr)*lda0 + (k0 + lk));
    else
      av = *(const float4*)(A1 + (size_t)(m0+lr)*lda1 + (k0 + lk - K0));
    float4 wv = *(const float4*)(W + (size_t)(n0+lr)*K + (k0 + lk));
    As[lk+0][lr]=av.x; As[lk+1][lr]=av.y; As[lk+2][lr]=av.z; As[lk+3][lr]=av.w;
    Bs[lk+0][lr]=wv.x; Bs[lk+1][lr]=wv.y; Bs[lk+2][lr]=wv.z; Bs[lk+3][lr]=wv.w;
    __syncthreads();
    #pragma unroll
    for (int kk=0; kk<16; kk++){
      float a[4], bb[4];
      #pragma unroll
      for (int i=0;i<4;i++) a[i]  = As[kk][ty*4+i];
      #pragma unroll
      for (int j=0;j<4;j++) bb[j] = Bs[kk][tx*4+j];
      #pragma unroll
      for (int i=0;i<4;i++)
        #pragma unroll
        for (int j=0;j<4;j++)
          acc[i][j] += a[i]*bb[j];
    }
    __syncthreads();
  }
  #pragma unroll
  for (int i=0;i<4;i++){
    #pragma unroll
    for (int j=0;j<4;j++){
      int n = n0 + tx*4 + j;
      float v = acc[i][j] + bias[n];
      if (bias2) v += bias2[n];
      if (ACT==1) v = sigf(v);
      else if (ACT==2) v = tanhf(v);
      C[(size_t)(m0+ty*4+i)*N + n] = v;
    }
  }
}

// ---------------- Memory scan (sequential over t) ---------------------------
__global__ __launch_bounds__(256) void k_scan(
    const float* __restrict__ wbuf, const float* __restrict__ ebuf,
    const float* __restrict__ abuf, const float* __restrict__ Mv0,
    float* __restrict__ X2)
{
  const int b = blockIdx.x;
  const int d = threadIdx.x;
  __shared__ float ws[SM];
  float mem[SM];
  #pragma unroll
  for (int m=0;m<SM;m++) mem[m] = Mv0[m*DS + d];
  for (int t=0;t<SEQ;t++){
    const size_t row = (size_t)b*SEQ + t;
    if (d < SM) ws[d] = wbuf[row*SM + d];
    const float e = ebuf[row*DS + d];
    const float a = abuf[row*DS + d];
    __syncthreads();
    float r0=0.f,r1=0.f,r2=0.f,r3=0.f;
    #pragma unroll
    for (int m=0;m<SM;m+=4){
      float w0=ws[m], w1=ws[m+1], w2=ws[m+2], w3=ws[m+3];
      r0 += w0*mem[m];   mem[m]   += w0*fmaf(-e, mem[m],   a);
      r1 += w1*mem[m+1]; mem[m+1] += w1*fmaf(-e, mem[m+1], a);
      r2 += w2*mem[m+2]; mem[m+2] += w2*fmaf(-e, mem[m+2], a);
      r3 += w3*mem[m+3]; mem[m+3] += w3*fmaf(-e, mem[m+3], a);
    }
    X2[row*512 + d] = (r0+r1)+(r2+r3);
    __syncthreads();
  }
}

// ---------------- Pairwise cooperative MFMA LSTM -----------------------------
// 8 blocks = 4 independent pairs. Pair p = bb>>1 owns batches [p*16,+16).
// Within a pair, block ro = bb&1 owns dims [ro*128,+128) (all 4 gates = 512
// W_hh rows in VGPRs). Per step: MFMA (M=16), in-lane gate fusion, write h to
// hhist + own LDS half; 2-party flag handshake; stage partner's 4KB half.
__global__ __launch_bounds__(512, 2) void k_lstm2(
    const float* __restrict__ gin, const float* __restrict__ W_hh,
    const float* __restrict__ hx, const float* __restrict__ cx,
    short* __restrict__ hhist, int* __restrict__ flags)
{
  const int bb = blockIdx.x;
  const int p  = bb >> 1;
  const int ro = bb & 1;
  const int tid = threadIdx.x;
  const int l   = tid & 63;
  const int w   = tid >> 6;

  __shared__ short hsm[2][16*256];   // 2 x 8KB, 512B rows, XOR-swizzled

  // W_hh B-fragments: G = gt*256 + ro*128 + w*16 + (l&15), k = kt*32+(l>>4)*8+j
  bf16x8 wfr[4][8];
  {
    const int col  = l & 15;
    const int krow = (l >> 4) * 8;
    #pragma unroll
    for (int gt=0; gt<4; gt++){
      const int G = gt*256 + ro*128 + w*16 + col;
      const float* wrow = W_hh + (size_t)G*256;
      #pragma unroll
      for (int kt=0; kt<8; kt++){
        const int k0 = kt*32 + krow;
        float4 wa = *(const float4*)(wrow + k0);
        float4 wb = *(const float4*)(wrow + k0 + 4);
        bf16x8 f;
        f[0]=f2bf(wa.x); f[1]=f2bf(wa.y); f[2]=f2bf(wa.z); f[3]=f2bf(wa.w);
        f[4]=f2bf(wb.x); f[5]=f2bf(wb.y); f[6]=f2bf(wb.z); f[7]=f2bf(wb.w);
        wfr[gt][kt] = f;
      }
    }
  }

  const int gdim = ro*128 + w*16 + (l & 15);   // this lane's dim
  float c_[4];
  {
    float c0 = cx[gdim];
    #pragma unroll
    for (int r=0;r<4;r++) c_[r] = c0;
  }

  // stage hx (broadcast) into hsm[0], full 256 dims for 16 rows
  if (tid < 256){
    const int row = tid >> 4, seg = tid & 15;
    #pragma unroll
    for (int u=0; u<2; u++){
      const int kb = seg*32 + u*16;
      const int d0 = kb >> 1;
      float4 ha = *(const float4*)(hx + d0);
      float4 hb = *(const float4*)(hx + d0 + 4);
      bf16x8 v;
      v[0]=f2bf(ha.x); v[1]=f2bf(ha.y); v[2]=f2bf(ha.z); v[3]=f2bf(ha.w);
      v[4]=f2bf(hb.x); v[5]=f2bf(hb.y); v[6]=f2bf(hb.z); v[7]=f2bf(hb.w);
      *(bf16x8*)((char*)hsm[0] + row*512 + (kb ^ ((row&7)<<4))) = v;
    }
  }

  // prefetch gin[t=0]
  float gpre[16];
  #pragma unroll
  for (int gt=0; gt<4; gt++)
    #pragma unroll
    for (int r=0; r<4; r++){
      const int b = p*16 + (l>>4)*4 + r;
      gpre[gt*4+r] = gin[((size_t)(b*SEQ))*1024 + gt*256 + gdim];
    }

  for (int t=0; t<SEQ; t++){
    __syncthreads();   // hsm[t&1] staged
    const int cur = t & 1;

    // MFMA: gates (16 batches x 16 dims x 4 gate types)
    f32x4 acc[4];
    #pragma unroll
    for (int gt=0; gt<4; gt++) acc[gt] = (f32x4){0.f,0.f,0.f,0.f};
    const int r0 = l & 15;
    #pragma unroll
    for (int kt=0; kt<8; kt++){
      const int kbyte = kt*64 + (l>>4)*16;
      bf16x8 a = *(const bf16x8*)((const char*)hsm[cur] + r0*512 + (kbyte ^ ((r0&7)<<4)));
      #pragma unroll
      for (int gt=0; gt<4; gt++)
        acc[gt] = __builtin_amdgcn_mfma_f32_16x16x32_bf16(a, wfr[gt][kt], acc[gt], 0,0,0);
    }

    // in-lane gate fusion + c/h update; write hhist + own LDS half for t+1
    #pragma unroll
    for (int r=0; r<4; r++){
      const int b = p*16 + (l>>4)*4 + r;
      float iv = gpre[0*4+r] + acc[0][r];
      float fv = gpre[1*4+r] + acc[1][r];
      float gv = gpre[2*4+r] + acc[2][r];
      float ov = gpre[3*4+r] + acc[3][r];
      float cc = fast_sig(fv)*c_[r] + fast_sig(iv)*fast_tanh(gv);
      c_[r] = cc;
      float h = fast_sig(ov)*fast_tanh(cc);
      short hb = f2bf(h);
      hhist[((size_t)(b*SEQ + t))*256 + gdim] = hb;
      const int bl = (l>>4)*4 + r;
      *(short*)((char*)hsm[cur^1] + bl*512 + ((gdim*2) ^ ((bl&7)<<4))) = hb;
    }

    if (t == SEQ-1) break;

    __syncthreads();   // barrier drain => all h writes at L2
    if (tid == 0){
      __threadfence();   // L2 writeback => globally visible
      __hip_atomic_store(&flags[bb*16], t+1, __ATOMIC_RELEASE, __HIP_MEMORY_SCOPE_AGENT);
    }
    // prefetch gin[t+1] while the handshake round-trips
    #pragma unroll
    for (int gt=0; gt<4; gt++)
      #pragma unroll
      for (int r=0; r<4; r++){
        const int b = p*16 + (l>>4)*4 + r;
        gpre[gt*4+r] = gin[((size_t)(b*SEQ + t+1))*1024 + gt*256 + gdim];
      }
    if (tid == 0){
      while (__hip_atomic_load(&flags[(bb^1)*16], __ATOMIC_ACQUIRE, __HIP_MEMORY_SCOPE_AGENT) < t+1)
        __builtin_amdgcn_s_sleep(1);
      __threadfence();
    }
    __syncthreads();

    // stage partner's dim-half of h(t) into hsm[cur^1] (4KB)
    if (tid < 256){
      const int row = tid >> 4, seg = tid & 15;
      const int kb = (1-ro)*256 + seg*16;
      const int b = p*16 + row;
      bf16x8 v = *(const bf16x8*)(hhist + ((size_t)(b*SEQ + t))*256 + (kb>>1));
      *(bf16x8*)((char*)hsm[cur^1] + row*512 + (kb ^ ((row&7)<<4))) = v;
    }
  }
}

// ---------------- p output: sigmoid(h . W_p + b_p) --------------------------
__global__ __launch_bounds__(256) void k_pout(
    const short* __restrict__ hhist, const float* __restrict__ W_p,
    const float* __restrict__ b_p, float* __restrict__ out)
{
  const int tid = threadIdx.x;
  const int row = blockIdx.x*4 + (tid>>6);
  const int ln = tid & 63;
  ushort4 hv = ((const ushort4*)(hhist + (size_t)row*256))[ln];
  float4 wp = ((const float4*)W_p)[ln];
  float s = bf2f(hv.x)*wp.x + bf2f(hv.y)*wp.y + bf2f(hv.z)*wp.z + bf2f(hv.w)*wp.w;
  #pragma unroll
  for (int off=32; off; off>>=1) s += __shfl_xor(s, off);
  if (ln == 0) out[row] = sigf(s + b_p[0]);
}

extern "C" void kernel_launch(void* const* d_in, const int* in_sizes, int n_in,
                              void* d_out, int out_size, void* d_ws, size_t ws_size,
                              hipStream_t stream)
{
  const int*   q     = (const int*)d_in[0];
  const int*   r     = (const int*)d_in[1];
  const float* k_emb = (const float*)d_in[2];
  const float* x_emb = (const float*)d_in[3];
  const float* Mk    = (const float*)d_in[4];
  const float* Mv0   = (const float*)d_in[5];
  const float* W_a   = (const float*)d_in[6];
  const float* b_a   = (const float*)d_in[7];
  const float* W_e   = (const float*)d_in[8];
  const float* b_e   = (const float*)d_in[9];
  const float* W_add = (const float*)d_in[10];
  const float* b_add = (const float*)d_in[11];
  const float* W_f   = (const float*)d_in[12];
  const float* b_f   = (const float*)d_in[13];
  const float* hx    = (const float*)d_in[14];
  const float* cx    = (const float*)d_in[15];
  const float* W_ih  = (const float*)d_in[16];
  const float* b_ih  = (const float*)d_in[17];
  const float* W_hh  = (const float*)d_in[18];
  const float* b_hh  = (const float*)d_in[19];
  const float* W_p   = (const float*)d_in[20];
  const float* b_p   = (const float*)d_in[21];
  float* out = (float*)d_out;

  float* ws    = (float*)d_ws;
  float* vbuf  = ws;
  float* webuf = vbuf  + (size_t)NROWS*DS;
  float* ebuf  = webuf + (size_t)NROWS*DS;
  float* abuf  = ebuf  + (size_t)NROWS*DS;
  float* gin   = vbuf;                            // overlay (vbuf..abuf dead)
  float* X2    = abuf  + (size_t)NROWS*DS;        // [reads|k]
  float* wbuf  = X2    + (size_t)NROWS*512;
  float* fbuf  = wbuf  + (size_t)NROWS*SM;
  short* hhist = (short*)fbuf;                    // overlays fbuf (dead)
  int*   flags = (int*)wbuf;                      // overlays wbuf (dead after scan)

  k_gather_attn<<<NROWS/4, 256, 0, stream>>>(q, r, k_emb, x_emb, Mk, X2, vbuf, wbuf);
  k_gemm<0><<<dim3(NROWS/64, 4), 256, 0, stream>>>(X2+DS, 512, DS, vbuf, DS, DS, W_a, b_a, nullptr, webuf, DS);
  k_gemm<1><<<dim3(NROWS/64, 4), 256, 0, stream>>>(webuf, DS, DS, nullptr, 0, 0, W_e,   b_e,   nullptr, ebuf, DS);
  k_gemm<2><<<dim3(NROWS/64, 4), 256, 0, stream>>>(webuf, DS, DS, nullptr, 0, 0, W_add, b_add, nullptr, abuf, DS);
  k_scan<<<BS, DS, 0, stream>>>(wbuf, ebuf, abuf, Mv0, X2);
  k_gemm<2><<<dim3(NROWS/64, 4), 256, 0, stream>>>(X2, 512, DS, X2+DS, 512, DS, W_f, b_f, nullptr, fbuf, DS);
  k_gemm<0><<<dim3(NROWS/64, 16), 256, 0, stream>>>(fbuf, DS, DS, nullptr, 0, 0, W_ih, b_ih, b_hh, gin, 1024);
  hipMemsetAsync((void*)flags, 0, LBLK*16*sizeof(int), stream);
  {
    const float* gin_c = gin;
    void* args[] = { (void*)&gin_c, (void*)&W_hh, (void*)&hx, (void*)&cx,
                     (void*)&hhist, (void*)&flags };
    hipLaunchCooperativeKernel((void*)k_lstm2, dim3(LBLK), dim3(512), args, 0, stream);
  }
  k_pout<<<NROWS/4, 256, 0, stream>>>(hhist, W_p, b_p, out);
}

// Round 4
// 1108.469 us; speedup vs baseline: 5.7294x; 1.2766x over previous
//
#include <hip/hip_runtime.h>
#include <hip/hip_bf16.h>

#define BS 64
#define SEQ 200
#define NSK 4096
#define DS 256
#define SM 64
#define NROWS (BS*SEQ)
#define LBLK 8   // 4 independent pairs x 2 blocks

typedef __attribute__((ext_vector_type(8))) short bf16x8;
typedef __attribute__((ext_vector_type(4))) float f32x4;

__device__ __forceinline__ float sigf(float x){ return 1.0f/(1.0f+expf(-x)); }
__device__ __forceinline__ float fast_sig(float x){ return 1.0f/(1.0f+__expf(-x)); }
__device__ __forceinline__ float fast_tanh(float x){
  float t = __expf(-2.0f*fabsf(x));
  float r = (1.0f - t)/(1.0f + t);
  return copysignf(r, x);
}
__device__ __forceinline__ short f2bf(float x){
  unsigned int u = __float_as_uint(x);
  unsigned int r = (u + 0x7fffu + ((u >> 16) & 1u)) >> 16;
  return (short)r;
}
__device__ __forceinline__ float bf2f(unsigned short s){
  return __uint_as_float(((unsigned int)s) << 16);
}

// ---------------- Kernel A: gather k,v + attention softmax w ----------------
__global__ __launch_bounds__(256) void k_gather_attn(
    const int* __restrict__ q, const int* __restrict__ r,
    const float* __restrict__ k_emb, const float* __restrict__ x_emb,
    const float* __restrict__ Mk,
    float* __restrict__ X2, float* __restrict__ vbuf, float* __restrict__ wbuf)
{
  __shared__ float ks[4][DS];
  const int tid = threadIdx.x;
  const int wv = tid >> 6, ln = tid & 63;
  const int row = blockIdx.x * 4 + wv;
  const int b = row / SEQ, s = row % SEQ;
  const int qi = q[b*SEQ + s];
  const int ri = r[b*SEQ + s];
  const float4* kr = (const float4*)(k_emb + (size_t)qi * DS);
  const float4* vr = (const float4*)(x_emb + ((size_t)qi + (size_t)NSK * ri) * DS);
  float4 kv = kr[ln];
  float4 vv = vr[ln];
  ((float4*)(X2 + (size_t)row*512 + DS))[ln] = kv;
  ((float4*)(vbuf + (size_t)row*DS))[ln] = vv;
  *((float4*)&ks[wv][ln*4]) = kv;
  __syncthreads();
  const float4* mkr = (const float4*)(Mk + (size_t)ln * DS);
  float a0=0.f,a1=0.f,a2=0.f,a3=0.f;
  #pragma unroll 8
  for (int d4=0; d4<DS/4; d4++){
    float4 m4 = mkr[d4];
    float4 k4 = *((const float4*)&ks[wv][d4*4]);
    a0 += m4.x*k4.x; a1 += m4.y*k4.y; a2 += m4.z*k4.z; a3 += m4.w*k4.w;
  }
  float lg = (a0+a1)+(a2+a3);
  float mx = lg;
  #pragma unroll
  for (int off=32; off; off>>=1) mx = fmaxf(mx, __shfl_xor(mx, off));
  float ex = expf(lg - mx);
  float sm = ex;
  #pragma unroll
  for (int off=32; off; off>>=1) sm += __shfl_xor(sm, off);
  wbuf[(size_t)row*SM + ln] = ex / sm;
}

// ---------------- bf16 MFMA GEMM: C = act(A @ W^T + bias [+bias2]) ----------
// A split in K: K0 cols from A0 (lda0), K1 from A1 (lda1). W row-major (N,K).
// 64x64 tile, 4 waves: wave w -> M-half (w>>1), N-half (w&1); 2x2 16x16 tiles.
// LDS rows 80B stride: read/write patterns are 2-way conflicts (free).
template<int ACT>  // 0 none, 1 sigmoid, 2 tanh
__global__ __launch_bounds__(256) void k_gemm_bf16(
    const float* __restrict__ A0, int lda0, int K0,
    const float* __restrict__ A1, int lda1, int K1,
    const float* __restrict__ W, const float* __restrict__ bias,
    const float* __restrict__ bias2,
    float* __restrict__ C, int N)
{
  const int K = K0 + K1;
  __shared__ __align__(16) char As[64*80];
  __shared__ __align__(16) char Bs[64*80];
  const int tid = threadIdx.x;
  const int l = tid & 63, w = tid >> 6;
  const int m0 = blockIdx.x * 64, n0 = blockIdx.y * 64;
  const int mh = w >> 1, nh = w & 1;
  const int srow = tid >> 2, sseg = tid & 3;

  f32x4 acc[2][2];
  #pragma unroll
  for (int i=0;i<2;i++)
    #pragma unroll
    for (int j=0;j<2;j++) acc[i][j] = (f32x4){0.f,0.f,0.f,0.f};

  for (int k0=0; k0<K; k0+=32){
    const int kk = k0 + sseg*8;
    const float* ap;
    if (kk < K0) ap = A0 + (size_t)(m0+srow)*lda0 + kk;
    else         ap = A1 + (size_t)(m0+srow)*lda1 + (kk - K0);
    float4 a1 = *(const float4*)ap;
    float4 a2 = *(const float4*)(ap+4);
    bf16x8 av;
    av[0]=f2bf(a1.x); av[1]=f2bf(a1.y); av[2]=f2bf(a1.z); av[3]=f2bf(a1.w);
    av[4]=f2bf(a2.x); av[5]=f2bf(a2.y); av[6]=f2bf(a2.z); av[7]=f2bf(a2.w);
    *(bf16x8*)(As + srow*80 + ((sseg ^ (srow&3))*16)) = av;
    const float* wp = W + (size_t)(n0+srow)*K + kk;
    float4 b1 = *(const float4*)wp;
    float4 b2 = *(const float4*)(wp+4);
    bf16x8 bv;
    bv[0]=f2bf(b1.x); bv[1]=f2bf(b1.y); bv[2]=f2bf(b1.z); bv[3]=f2bf(b1.w);
    bv[4]=f2bf(b2.x); bv[5]=f2bf(b2.y); bv[6]=f2bf(b2.z); bv[7]=f2bf(b2.w);
    *(bf16x8*)(Bs + srow*80 + ((sseg ^ (srow&3))*16)) = bv;
    __syncthreads();
    bf16x8 af[2], bf[2];
    #pragma unroll
    for (int mi=0; mi<2; mi++){
      const int row = mh*32 + mi*16 + (l&15);
      af[mi] = *(const bf16x8*)(As + row*80 + (((l>>4) ^ (row&3))*16));
    }
    #pragma unroll
    for (int ni=0; ni<2; ni++){
      const int row = nh*32 + ni*16 + (l&15);
      bf[ni] = *(const bf16x8*)(Bs + row*80 + (((l>>4) ^ (row&3))*16));
    }
    #pragma unroll
    for (int mi=0; mi<2; mi++)
      #pragma unroll
      for (int ni=0; ni<2; ni++)
        acc[mi][ni] = __builtin_amdgcn_mfma_f32_16x16x32_bf16(af[mi], bf[ni], acc[mi][ni], 0,0,0);
    __syncthreads();
  }
  #pragma unroll
  for (int mi=0; mi<2; mi++){
    #pragma unroll
    for (int ni=0; ni<2; ni++){
      const int n = n0 + nh*32 + ni*16 + (l&15);
      float bsum = bias[n] + (bias2 ? bias2[n] : 0.f);
      #pragma unroll
      for (int j=0;j<4;j++){
        const int m = m0 + mh*32 + mi*16 + (l>>4)*4 + j;
        float v = acc[mi][ni][j] + bsum;
        if (ACT==1) v = sigf(v);
        else if (ACT==2) v = tanhf(v);
        C[(size_t)m*N + n] = v;
      }
    }
  }
}

// ---------------- Memory scan (sequential over t) ---------------------------
__global__ __launch_bounds__(256) void k_scan(
    const float* __restrict__ wbuf, const float* __restrict__ ebuf,
    const float* __restrict__ abuf, const float* __restrict__ Mv0,
    float* __restrict__ X2)
{
  const int b = blockIdx.x;
  const int d = threadIdx.x;
  __shared__ float ws[SM];
  float mem[SM];
  #pragma unroll
  for (int m=0;m<SM;m++) mem[m] = Mv0[m*DS + d];
  for (int t=0;t<SEQ;t++){
    const size_t row = (size_t)b*SEQ + t;
    if (d < SM) ws[d] = wbuf[row*SM + d];
    const float e = ebuf[row*DS + d];
    const float a = abuf[row*DS + d];
    __syncthreads();
    float r0=0.f,r1=0.f,r2=0.f,r3=0.f;
    #pragma unroll
    for (int m=0;m<SM;m+=4){
      float w0=ws[m], w1=ws[m+1], w2=ws[m+2], w3=ws[m+3];
      r0 += w0*mem[m];   mem[m]   += w0*fmaf(-e, mem[m],   a);
      r1 += w1*mem[m+1]; mem[m+1] += w1*fmaf(-e, mem[m+1], a);
      r2 += w2*mem[m+2]; mem[m+2] += w2*fmaf(-e, mem[m+2], a);
      r3 += w3*mem[m+3]; mem[m+3] += w3*fmaf(-e, mem[m+3], a);
    }
    X2[row*512 + d] = (r0+r1)+(r2+r3);
    __syncthreads();
  }
}

// ---------------- Pairwise cooperative MFMA LSTM (atomic exchange) ----------
// 8 blocks = 4 pairs. Pair p owns batches [16p,+16). Block ro = bb&1 owns dims
// [ro*128,+128), all 4 gates (512 W_hh rows in VGPRs). Cross-block h exchange
// via agent-scope atomics (coherent point) -- no cache-wide fences.
__global__ __launch_bounds__(512, 2) void k_lstm2(
    const float* __restrict__ gin, const float* __restrict__ W_hh,
    const float* __restrict__ hx, const float* __restrict__ cx,
    short* __restrict__ hhist, int* __restrict__ flags,
    unsigned long long* __restrict__ xbuf)
{
  const int bb = blockIdx.x;
  const int p  = bb >> 1;
  const int ro = bb & 1;
  const int tid = threadIdx.x;
  const int l   = tid & 63;
  const int w   = tid >> 6;

  __shared__ short hsm[2][16*256];   // 2 x 8KB, 512B rows, XOR-swizzled

  bf16x8 wfr[4][8];
  {
    const int col  = l & 15;
    const int krow = (l >> 4) * 8;
    #pragma unroll
    for (int gt=0; gt<4; gt++){
      const int G = gt*256 + ro*128 + w*16 + col;
      const float* wrow = W_hh + (size_t)G*256;
      #pragma unroll
      for (int kt=0; kt<8; kt++){
        const int k0 = kt*32 + krow;
        float4 wa = *(const float4*)(wrow + k0);
        float4 wb = *(const float4*)(wrow + k0 + 4);
        bf16x8 f;
        f[0]=f2bf(wa.x); f[1]=f2bf(wa.y); f[2]=f2bf(wa.z); f[3]=f2bf(wa.w);
        f[4]=f2bf(wb.x); f[5]=f2bf(wb.y); f[6]=f2bf(wb.z); f[7]=f2bf(wb.w);
        wfr[gt][kt] = f;
      }
    }
  }

  const int gdim = ro*128 + w*16 + (l & 15);
  float c_[4];
  {
    float c0 = cx[gdim];
    #pragma unroll
    for (int r=0;r<4;r++) c_[r] = c0;
  }

  // stage hx into hsm[0] (full 256 dims, 16 rows)
  if (tid < 256){
    const int row = tid >> 4, seg = tid & 15;
    #pragma unroll
    for (int u=0; u<2; u++){
      const int kb = seg*32 + u*16;
      const int d0 = kb >> 1;
      float4 ha = *(const float4*)(hx + d0);
      float4 hb = *(const float4*)(hx + d0 + 4);
      bf16x8 v;
      v[0]=f2bf(ha.x); v[1]=f2bf(ha.y); v[2]=f2bf(ha.z); v[3]=f2bf(ha.w);
      v[4]=f2bf(hb.x); v[5]=f2bf(hb.y); v[6]=f2bf(hb.z); v[7]=f2bf(hb.w);
      *(bf16x8*)((char*)hsm[0] + row*512 + (kb ^ ((row&7)<<4))) = v;
    }
  }

  // prefetch gin[t=0]
  float gpre[16];
  #pragma unroll
  for (int gt=0; gt<4; gt++)
    #pragma unroll
    for (int r=0; r<4; r++){
      const int b = p*16 + (l>>4)*4 + r;
      gpre[gt*4+r] = gin[((size_t)(b*SEQ))*1024 + gt*256 + gdim];
    }

  for (int t=0; t<SEQ; t++){
    __syncthreads();   // hsm[t&1] fully staged
    const int cur = t & 1;

    f32x4 acc[4];
    #pragma unroll
    for (int gt=0; gt<4; gt++) acc[gt] = (f32x4){0.f,0.f,0.f,0.f};
    const int r0 = l & 15;
    #pragma unroll
    for (int kt=0; kt<8; kt++){
      const int kbyte = kt*64 + (l>>4)*16;
      bf16x8 a = *(const bf16x8*)((const char*)hsm[cur] + r0*512 + (kbyte ^ ((r0&7)<<4)));
      #pragma unroll
      for (int gt=0; gt<4; gt++)
        acc[gt] = __builtin_amdgcn_mfma_f32_16x16x32_bf16(a, wfr[gt][kt], acc[gt], 0,0,0);
    }

    #pragma unroll
    for (int r=0; r<4; r++){
      const int b = p*16 + (l>>4)*4 + r;
      float iv = gpre[0*4+r] + acc[0][r];
      float fv = gpre[1*4+r] + acc[1][r];
      float gv = gpre[2*4+r] + acc[2][r];
      float ov = gpre[3*4+r] + acc[3][r];
      float cc = fast_sig(fv)*c_[r] + fast_sig(iv)*fast_tanh(gv);
      c_[r] = cc;
      float h = fast_sig(ov)*fast_tanh(cc);
      short hb = f2bf(h);
      hhist[((size_t)(b*SEQ + t))*256 + gdim] = hb;   // plain store; read post-kernel
      const int bl = (l>>4)*4 + r;
      *(short*)((char*)hsm[cur^1] + bl*512 + ((gdim*2) ^ ((bl&7)<<4))) = hb;
    }

    if (t == SEQ-1) break;

    __syncthreads();   // own half complete in hsm[cur^1]

    // exchange-out: 512 threads x 8B agent-atomic store of own half
    {
      const int bat = tid >> 5, ch = tid & 31;
      const int o = ro*256 + ch*8;
      unsigned long long v8 = *(const unsigned long long*)
          ((const char*)hsm[cur^1] + bat*512 + (o ^ ((bat&7)<<4)));
      __hip_atomic_store(&xbuf[(size_t)((p*2 + (t&1))*2 + ro)*512 + tid], v8,
                         __ATOMIC_RELAXED, __HIP_MEMORY_SCOPE_AGENT);
    }
    asm volatile("s_waitcnt vmcnt(0)" ::: "memory");   // this wave's stores acked
    __syncthreads();                                    // all waves' stores acked
    if (tid == 0)
      __hip_atomic_store(&flags[bb*32], t+1, __ATOMIC_RELAXED, __HIP_MEMORY_SCOPE_AGENT);

    // prefetch gin[t+1] while partner's data is in flight
    #pragma unroll
    for (int gt=0; gt<4; gt++)
      #pragma unroll
      for (int r=0; r<4; r++){
        const int b = p*16 + (l>>4)*4 + r;
        gpre[gt*4+r] = gin[((size_t)(b*SEQ + t+1))*1024 + gt*256 + gdim];
      }

    if (tid == 0){
      while (__hip_atomic_fetch_add(&flags[(bb^1)*32], 0, __ATOMIC_RELAXED,
                                    __HIP_MEMORY_SCOPE_AGENT) < t+1)
        __builtin_amdgcn_s_sleep(1);
    }
    __syncthreads();
    asm volatile("" ::: "memory");

    // exchange-in: 512 threads x 8B agent-atomic load of partner half
    {
      const int bat = tid >> 5, ch = tid & 31;
      unsigned long long v8 = __hip_atomic_load(
          &xbuf[(size_t)((p*2 + (t&1))*2 + (1-ro))*512 + tid],
          __ATOMIC_RELAXED, __HIP_MEMORY_SCOPE_AGENT);
      const int o = (1-ro)*256 + ch*8;
      *(unsigned long long*)((char*)hsm[cur^1] + bat*512 + (o ^ ((bat&7)<<4))) = v8;
    }
    // next-iteration top __syncthreads covers LDS visibility
  }
}

// ---------------- p output: sigmoid(h . W_p + b_p) --------------------------
__global__ __launch_bounds__(256) void k_pout(
    const short* __restrict__ hhist, const float* __restrict__ W_p,
    const float* __restrict__ b_p, float* __restrict__ out)
{
  const int tid = threadIdx.x;
  const int row = blockIdx.x*4 + (tid>>6);
  const int ln = tid & 63;
  ushort4 hv = ((const ushort4*)(hhist + (size_t)row*256))[ln];
  float4 wp = ((const float4*)W_p)[ln];
  float s = bf2f(hv.x)*wp.x + bf2f(hv.y)*wp.y + bf2f(hv.z)*wp.z + bf2f(hv.w)*wp.w;
  #pragma unroll
  for (int off=32; off; off>>=1) s += __shfl_xor(s, off);
  if (ln == 0) out[row] = sigf(s + b_p[0]);
}

extern "C" void kernel_launch(void* const* d_in, const int* in_sizes, int n_in,
                              void* d_out, int out_size, void* d_ws, size_t ws_size,
                              hipStream_t stream)
{
  const int*   q     = (const int*)d_in[0];
  const int*   r     = (const int*)d_in[1];
  const float* k_emb = (const float*)d_in[2];
  const float* x_emb = (const float*)d_in[3];
  const float* Mk    = (const float*)d_in[4];
  const float* Mv0   = (const float*)d_in[5];
  const float* W_a   = (const float*)d_in[6];
  const float* b_a   = (const float*)d_in[7];
  const float* W_e   = (const float*)d_in[8];
  const float* b_e   = (const float*)d_in[9];
  const float* W_add = (const float*)d_in[10];
  const float* b_add = (const float*)d_in[11];
  const float* W_f   = (const float*)d_in[12];
  const float* b_f   = (const float*)d_in[13];
  const float* hx    = (const float*)d_in[14];
  const float* cx    = (const float*)d_in[15];
  const float* W_ih  = (const float*)d_in[16];
  const float* b_ih  = (const float*)d_in[17];
  const float* W_hh  = (const float*)d_in[18];
  const float* b_hh  = (const float*)d_in[19];
  const float* W_p   = (const float*)d_in[20];
  const float* b_p   = (const float*)d_in[21];
  float* out = (float*)d_out;

  float* ws    = (float*)d_ws;
  float* vbuf  = ws;
  float* webuf = vbuf  + (size_t)NROWS*DS;
  float* ebuf  = webuf + (size_t)NROWS*DS;
  float* abuf  = ebuf  + (size_t)NROWS*DS;
  float* gin   = vbuf;                            // overlay (vbuf..abuf dead)
  float* X2    = abuf  + (size_t)NROWS*DS;        // [reads|k]
  float* wbuf  = X2    + (size_t)NROWS*512;
  float* fbuf  = wbuf  + (size_t)NROWS*SM;
  short* hhist = (short*)fbuf;                    // overlays fbuf (dead)
  int*   flags = (int*)wbuf;                      // overlays wbuf (dead after scan)
  unsigned long long* xbuf = (unsigned long long*)(fbuf + (size_t)NROWS*DS); // 64KB fresh

  k_gather_attn<<<NROWS/4, 256, 0, stream>>>(q, r, k_emb, x_emb, Mk, X2, vbuf, wbuf);
  k_gemm_bf16<0><<<dim3(NROWS/64, 4), 256, 0, stream>>>(X2+DS, 512, DS, vbuf, DS, DS, W_a, b_a, nullptr, webuf, DS);
  k_gemm_bf16<1><<<dim3(NROWS/64, 4), 256, 0, stream>>>(webuf, DS, DS, webuf, DS, 0, W_e,   b_e,   nullptr, ebuf, DS);
  k_gemm_bf16<2><<<dim3(NROWS/64, 4), 256, 0, stream>>>(webuf, DS, DS, webuf, DS, 0, W_add, b_add, nullptr, abuf, DS);
  k_scan<<<BS, DS, 0, stream>>>(wbuf, ebuf, abuf, Mv0, X2);
  k_gemm_bf16<2><<<dim3(NROWS/64, 4), 256, 0, stream>>>(X2, 512, DS, X2+DS, 512, DS, W_f, b_f, nullptr, fbuf, DS);
  k_gemm_bf16<0><<<dim3(NROWS/64, 16), 256, 0, stream>>>(fbuf, DS, DS, fbuf, DS, 0, W_ih, b_ih, b_hh, gin, 1024);
  hipMemsetAsync((void*)flags, 0, LBLK*32*sizeof(int), stream);
  {
    const float* gin_c = gin;
    void* args[] = { (void*)&gin_c, (void*)&W_hh, (void*)&hx, (void*)&cx,
                     (void*)&hhist, (void*)&flags, (void*)&xbuf };
    hipLaunchCooperativeKernel((void*)k_lstm2, dim3(LBLK), dim3(512), args, 0, stream);
  }
  k_pout<<<NROWS/4, 256, 0, stream>>>(hhist, W_p, b_p, out);
}

// Round 5
// 1028.870 us; speedup vs baseline: 6.1727x; 1.0774x over previous
//
#include <hip/hip_runtime.h>
#include <hip/hip_bf16.h>

#define BS 64
#define SEQ 200
#define NSK 4096
#define DS 256
#define SM 64
#define NROWS (BS*SEQ)
#define LBLK 8   // 4 independent pairs x 2 blocks

typedef __attribute__((ext_vector_type(8))) short bf16x8;
typedef __attribute__((ext_vector_type(4))) float f32x4;

__device__ __forceinline__ float sigf(float x){ return 1.0f/(1.0f+expf(-x)); }
__device__ __forceinline__ float fast_sig(float x){ return 1.0f/(1.0f+__expf(-x)); }
__device__ __forceinline__ float fast_tanh(float x){
  float t = __expf(-2.0f*fabsf(x));
  float r = (1.0f - t)/(1.0f + t);
  return copysignf(r, x);
}
__device__ __forceinline__ short f2bf(float x){
  unsigned int u = __float_as_uint(x);
  unsigned int r = (u + 0x7fffu + ((u >> 16) & 1u)) >> 16;
  return (short)r;
}
__device__ __forceinline__ float bf2f(unsigned short s){
  return __uint_as_float(((unsigned int)s) << 16);
}

// ---------------- Kernel A: gather k,v + attention softmax w ----------------
__global__ __launch_bounds__(256) void k_gather_attn(
    const int* __restrict__ q, const int* __restrict__ r,
    const float* __restrict__ k_emb, const float* __restrict__ x_emb,
    const float* __restrict__ Mk,
    float* __restrict__ X2, float* __restrict__ vbuf, float* __restrict__ wbuf)
{
  __shared__ float ks[4][DS];
  const int tid = threadIdx.x;
  const int wv = tid >> 6, ln = tid & 63;
  const int row = blockIdx.x * 4 + wv;
  const int b = row / SEQ, s = row % SEQ;
  const int qi = q[b*SEQ + s];
  const int ri = r[b*SEQ + s];
  const float4* kr = (const float4*)(k_emb + (size_t)qi * DS);
  const float4* vr = (const float4*)(x_emb + ((size_t)qi + (size_t)NSK * ri) * DS);
  float4 kv = kr[ln];
  float4 vv = vr[ln];
  ((float4*)(X2 + (size_t)row*512 + DS))[ln] = kv;
  ((float4*)(vbuf + (size_t)row*DS))[ln] = vv;
  *((float4*)&ks[wv][ln*4]) = kv;
  __syncthreads();
  const float4* mkr = (const float4*)(Mk + (size_t)ln * DS);
  float a0=0.f,a1=0.f,a2=0.f,a3=0.f;
  #pragma unroll 8
  for (int d4=0; d4<DS/4; d4++){
    float4 m4 = mkr[d4];
    float4 k4 = *((const float4*)&ks[wv][d4*4]);
    a0 += m4.x*k4.x; a1 += m4.y*k4.y; a2 += m4.z*k4.z; a3 += m4.w*k4.w;
  }
  float lg = (a0+a1)+(a2+a3);
  float mx = lg;
  #pragma unroll
  for (int off=32; off; off>>=1) mx = fmaxf(mx, __shfl_xor(mx, off));
  float ex = expf(lg - mx);
  float sm = ex;
  #pragma unroll
  for (int off=32; off; off>>=1) sm += __shfl_xor(sm, off);
  wbuf[(size_t)row*SM + ln] = ex / sm;
}

// ---------------- bf16 MFMA GEMM: C = act(A @ W^T + bias [+bias2]) ----------
template<int ACT>  // 0 none, 1 sigmoid, 2 tanh
__global__ __launch_bounds__(256) void k_gemm_bf16(
    const float* __restrict__ A0, int lda0, int K0,
    const float* __restrict__ A1, int lda1, int K1,
    const float* __restrict__ W, const float* __restrict__ bias,
    const float* __restrict__ bias2,
    float* __restrict__ C, int N)
{
  const int K = K0 + K1;
  __shared__ __align__(16) char As[64*80];
  __shared__ __align__(16) char Bs[64*80];
  const int tid = threadIdx.x;
  const int l = tid & 63, w = tid >> 6;
  const int m0 = blockIdx.x * 64, n0 = blockIdx.y * 64;
  const int mh = w >> 1, nh = w & 1;
  const int srow = tid >> 2, sseg = tid & 3;

  f32x4 acc[2][2];
  #pragma unroll
  for (int i=0;i<2;i++)
    #pragma unroll
    for (int j=0;j<2;j++) acc[i][j] = (f32x4){0.f,0.f,0.f,0.f};

  for (int k0=0; k0<K; k0+=32){
    const int kk = k0 + sseg*8;
    const float* ap;
    if (kk < K0) ap = A0 + (size_t)(m0+srow)*lda0 + kk;
    else         ap = A1 + (size_t)(m0+srow)*lda1 + (kk - K0);
    float4 a1 = *(const float4*)ap;
    float4 a2 = *(const float4*)(ap+4);
    bf16x8 av;
    av[0]=f2bf(a1.x); av[1]=f2bf(a1.y); av[2]=f2bf(a1.z); av[3]=f2bf(a1.w);
    av[4]=f2bf(a2.x); av[5]=f2bf(a2.y); av[6]=f2bf(a2.z); av[7]=f2bf(a2.w);
    *(bf16x8*)(As + srow*80 + ((sseg ^ (srow&3))*16)) = av;
    const float* wp = W + (size_t)(n0+srow)*K + kk;
    float4 b1 = *(const float4*)wp;
    float4 b2 = *(const float4*)(wp+4);
    bf16x8 bv;
    bv[0]=f2bf(b1.x); bv[1]=f2bf(b1.y); bv[2]=f2bf(b1.z); bv[3]=f2bf(b1.w);
    bv[4]=f2bf(b2.x); bv[5]=f2bf(b2.y); bv[6]=f2bf(b2.z); bv[7]=f2bf(b2.w);
    *(bf16x8*)(Bs + srow*80 + ((sseg ^ (srow&3))*16)) = bv;
    __syncthreads();
    bf16x8 af[2], bf[2];
    #pragma unroll
    for (int mi=0; mi<2; mi++){
      const int row = mh*32 + mi*16 + (l&15);
      af[mi] = *(const bf16x8*)(As + row*80 + (((l>>4) ^ (row&3))*16));
    }
    #pragma unroll
    for (int ni=0; ni<2; ni++){
      const int row = nh*32 + ni*16 + (l&15);
      bf[ni] = *(const bf16x8*)(Bs + row*80 + (((l>>4) ^ (row&3))*16));
    }
    #pragma unroll
    for (int mi=0; mi<2; mi++)
      #pragma unroll
      for (int ni=0; ni<2; ni++)
        acc[mi][ni] = __builtin_amdgcn_mfma_f32_16x16x32_bf16(af[mi], bf[ni], acc[mi][ni], 0,0,0);
    __syncthreads();
  }
  #pragma unroll
  for (int mi=0; mi<2; mi++){
    #pragma unroll
    for (int ni=0; ni<2; ni++){
      const int n = n0 + nh*32 + ni*16 + (l&15);
      float bsum = bias[n] + (bias2 ? bias2[n] : 0.f);
      #pragma unroll
      for (int j=0;j<4;j++){
        const int m = m0 + mh*32 + mi*16 + (l>>4)*4 + j;
        float v = acc[mi][ni][j] + bsum;
        if (ACT==1) v = sigf(v);
        else if (ACT==2) v = tanhf(v);
        C[(size_t)m*N + n] = v;
      }
    }
  }
}

// ---------------- Memory scan (sequential over t) ---------------------------
__global__ __launch_bounds__(256) void k_scan(
    const float* __restrict__ wbuf, const float* __restrict__ ebuf,
    const float* __restrict__ abuf, const float* __restrict__ Mv0,
    float* __restrict__ X2)
{
  const int b = blockIdx.x;
  const int d = threadIdx.x;
  __shared__ float ws[SM];
  float mem[SM];
  #pragma unroll
  for (int m=0;m<SM;m++) mem[m] = Mv0[m*DS + d];
  for (int t=0;t<SEQ;t++){
    const size_t row = (size_t)b*SEQ + t;
    if (d < SM) ws[d] = wbuf[row*SM + d];
    const float e = ebuf[row*DS + d];
    const float a = abuf[row*DS + d];
    __syncthreads();
    float r0=0.f,r1=0.f,r2=0.f,r3=0.f;
    #pragma unroll
    for (int m=0;m<SM;m+=4){
      float w0=ws[m], w1=ws[m+1], w2=ws[m+2], w3=ws[m+3];
      r0 += w0*mem[m];   mem[m]   += w0*fmaf(-e, mem[m],   a);
      r1 += w1*mem[m+1]; mem[m+1] += w1*fmaf(-e, mem[m+1], a);
      r2 += w2*mem[m+2]; mem[m+2] += w2*fmaf(-e, mem[m+2], a);
      r3 += w3*mem[m+3]; mem[m+3] += w3*fmaf(-e, mem[m+3], a);
    }
    X2[row*512 + d] = (r0+r1)+(r2+r3);
    __syncthreads();
  }
}

// ---------------- Pairwise cooperative MFMA LSTM (tagged-slot exchange) -----
// 8 blocks = 4 pairs. Pair p owns batches [16p,+16). Block ro = bb&1 owns dims
// [ro*128,+128), all 4 gates (512 W_hh rows in VGPRs). Cross-block h exchange
// via 64-bit tagged slots: (h_even<<48)|(h_odd<<32)|step_tag — merges data and
// flag, single coherent hop + poll; no fences, one barrier per step.
__global__ __launch_bounds__(512, 2) void k_lstm2(
    const float* __restrict__ gin, const float* __restrict__ W_hh,
    const float* __restrict__ hx, const float* __restrict__ cx,
    short* __restrict__ hhist, unsigned long long* __restrict__ xbuf)
{
  const int bb = blockIdx.x;
  const int p  = bb >> 1;
  const int ro = bb & 1;
  const int tid = threadIdx.x;
  const int l   = tid & 63;
  const int w   = tid >> 6;

  __shared__ short hsm[2][16*256];   // 2 x 8KB, 512B rows, XOR-swizzled

  bf16x8 wfr[4][8];
  {
    const int col  = l & 15;
    const int krow = (l >> 4) * 8;
    #pragma unroll
    for (int gt=0; gt<4; gt++){
      const int G = gt*256 + ro*128 + w*16 + col;
      const float* wrow = W_hh + (size_t)G*256;
      #pragma unroll
      for (int kt=0; kt<8; kt++){
        const int k0 = kt*32 + krow;
        float4 wa = *(const float4*)(wrow + k0);
        float4 wb = *(const float4*)(wrow + k0 + 4);
        bf16x8 f;
        f[0]=f2bf(wa.x); f[1]=f2bf(wa.y); f[2]=f2bf(wa.z); f[3]=f2bf(wa.w);
        f[4]=f2bf(wb.x); f[5]=f2bf(wb.y); f[6]=f2bf(wb.z); f[7]=f2bf(wb.w);
        wfr[gt][kt] = f;
      }
    }
  }

  const int dhalf = w*16 + (l & 15);           // 0..127 within my half
  const int gdim  = ro*128 + dhalf;            // this lane's dim
  float c_[4];
  {
    float c0 = cx[gdim];
    #pragma unroll
    for (int r=0;r<4;r++) c_[r] = c0;
  }

  // stage hx into hsm[0] (full 256 dims, 16 rows)
  if (tid < 256){
    const int row = tid >> 4, seg = tid & 15;
    #pragma unroll
    for (int u=0; u<2; u++){
      const int kb = seg*32 + u*16;
      const int d0 = kb >> 1;
      float4 ha = *(const float4*)(hx + d0);
      float4 hb = *(const float4*)(hx + d0 + 4);
      bf16x8 v;
      v[0]=f2bf(ha.x); v[1]=f2bf(ha.y); v[2]=f2bf(ha.z); v[3]=f2bf(ha.w);
      v[4]=f2bf(hb.x); v[5]=f2bf(hb.y); v[6]=f2bf(hb.z); v[7]=f2bf(hb.w);
      *(bf16x8*)((char*)hsm[0] + row*512 + (kb ^ ((row&7)<<4))) = v;
    }
  }

  // prefetch gin[t=0]
  float gpre[16];
  #pragma unroll
  for (int gt=0; gt<4; gt++)
    #pragma unroll
    for (int r=0; r<4; r++){
      const int b = p*16 + (l>>4)*4 + r;
      gpre[gt*4+r] = gin[((size_t)(b*SEQ))*1024 + gt*256 + gdim];
    }

  // slot buffers: xbuf[(p*2+ro)*1024 + bat*64 + (dhalf>>1)]
  unsigned long long* myslots = xbuf + (size_t)(p*2 + ro)*1024;
  unsigned long long* pslots  = xbuf + (size_t)(p*2 + (1-ro))*1024;

  for (int t=0; t<SEQ; t++){
    __syncthreads();   // hsm[t&1] fully staged
    const int cur = t & 1;

    f32x4 acc[4];
    #pragma unroll
    for (int gt=0; gt<4; gt++) acc[gt] = (f32x4){0.f,0.f,0.f,0.f};
    const int r0 = l & 15;
    #pragma unroll
    for (int kt=0; kt<8; kt++){
      const int kbyte = kt*64 + (l>>4)*16;
      bf16x8 a = *(const bf16x8*)((const char*)hsm[cur] + r0*512 + (kbyte ^ ((r0&7)<<4)));
      #pragma unroll
      for (int gt=0; gt<4; gt++)
        acc[gt] = __builtin_amdgcn_mfma_f32_16x16x32_bf16(a, wfr[gt][kt], acc[gt], 0,0,0);
    }

    const unsigned int tag = (unsigned int)(t + 1);
    #pragma unroll
    for (int r=0; r<4; r++){
      const int bat = (l>>4)*4 + r;            // block-local batch
      const int b = p*16 + bat;
      float iv = gpre[0*4+r] + acc[0][r];
      float fv = gpre[1*4+r] + acc[1][r];
      float gv = gpre[2*4+r] + acc[2][r];
      float ov = gpre[3*4+r] + acc[3][r];
      float cc = fast_sig(fv)*c_[r] + fast_sig(iv)*fast_tanh(gv);
      c_[r] = cc;
      float h = fast_sig(ov)*fast_tanh(cc);
      unsigned short hb = (unsigned short)f2bf(h);
      hhist[((size_t)(b*SEQ + t))*256 + gdim] = (short)hb;   // plain; read post-kernel
      *(short*)((char*)hsm[cur^1] + bat*512 + ((gdim*2) ^ ((bat&7)<<4))) = (short)hb;
      // tagged-slot export (even-dim lanes pack self + neighbor)
      unsigned short nb = (unsigned short)__shfl_xor((int)hb, 1);
      if ((l & 1) == 0){
        unsigned long long v = ((unsigned long long)hb << 48)
                             | ((unsigned long long)nb << 32)
                             | (unsigned long long)tag;
        __hip_atomic_store(&myslots[bat*64 + (dhalf>>1)], v,
                           __ATOMIC_RELAXED, __HIP_MEMORY_SCOPE_AGENT);
      }
    }

    if (t == SEQ-1) break;

    // prefetch gin[t+1] while our stores propagate
    #pragma unroll
    for (int gt=0; gt<4; gt++)
      #pragma unroll
      for (int r=0; r<4; r++){
        const int b = p*16 + (l>>4)*4 + r;
        gpre[gt*4+r] = gin[((size_t)(b*SEQ + t+1))*1024 + gt*256 + gdim];
      }

    // poll partner's 2 slots; write partner half into hsm[cur^1]
    {
      const int s0 = tid*2, s1 = tid*2 + 1;
      unsigned long long v0=0, v1=0;
      bool ok0=false, ok1=false;
      while (true){
        if (!ok0){ v0 = __hip_atomic_load(&pslots[s0], __ATOMIC_RELAXED, __HIP_MEMORY_SCOPE_AGENT);
                   ok0 = ((unsigned int)v0 == tag); }
        if (!ok1){ v1 = __hip_atomic_load(&pslots[s1], __ATOMIC_RELAXED, __HIP_MEMORY_SCOPE_AGENT);
                   ok1 = ((unsigned int)v1 == tag); }
        if (ok0 && ok1) break;
        __builtin_amdgcn_s_sleep(1);
      }
      #pragma unroll
      for (int u=0; u<2; u++){
        unsigned long long v = u ? v1 : v0;
        const int sid = u ? s1 : s0;
        const int bat = sid >> 6;
        const int dp  = sid & 63;
        const int dpart = (1-ro)*128 + dp*2;
        unsigned int wv = (unsigned int)((v >> 48) & 0xffffu)
                        | (((unsigned int)(v >> 32) & 0xffffu) << 16);
        *(unsigned int*)((char*)hsm[cur^1] + bat*512 + ((dpart*2) ^ ((bat&7)<<4))) = wv;
      }
    }
    // next-iteration top __syncthreads covers LDS visibility
  }
}

// ---------------- p output: sigmoid(h . W_p + b_p) --------------------------
__global__ __launch_bounds__(256) void k_pout(
    const short* __restrict__ hhist, const float* __restrict__ W_p,
    const float* __restrict__ b_p, float* __restrict__ out)
{
  const int tid = threadIdx.x;
  const int row = blockIdx.x*4 + (tid>>6);
  const int ln = tid & 63;
  ushort4 hv = ((const ushort4*)(hhist + (size_t)row*256))[ln];
  float4 wp = ((const float4*)W_p)[ln];
  float s = bf2f(hv.x)*wp.x + bf2f(hv.y)*wp.y + bf2f(hv.z)*wp.z + bf2f(hv.w)*wp.w;
  #pragma unroll
  for (int off=32; off; off>>=1) s += __shfl_xor(s, off);
  if (ln == 0) out[row] = sigf(s + b_p[0]);
}

extern "C" void kernel_launch(void* const* d_in, const int* in_sizes, int n_in,
                              void* d_out, int out_size, void* d_ws, size_t ws_size,
                              hipStream_t stream)
{
  const int*   q     = (const int*)d_in[0];
  const int*   r     = (const int*)d_in[1];
  const float* k_emb = (const float*)d_in[2];
  const float* x_emb = (const float*)d_in[3];
  const float* Mk    = (const float*)d_in[4];
  const float* Mv0   = (const float*)d_in[5];
  const float* W_a   = (const float*)d_in[6];
  const float* b_a   = (const float*)d_in[7];
  const float* W_e   = (const float*)d_in[8];
  const float* b_e   = (const float*)d_in[9];
  const float* W_add = (const float*)d_in[10];
  const float* b_add = (const float*)d_in[11];
  const float* W_f   = (const float*)d_in[12];
  const float* b_f   = (const float*)d_in[13];
  const float* hx    = (const float*)d_in[14];
  const float* cx    = (const float*)d_in[15];
  const float* W_ih  = (const float*)d_in[16];
  const float* b_ih  = (const float*)d_in[17];
  const float* W_hh  = (const float*)d_in[18];
  const float* b_hh  = (const float*)d_in[19];
  const float* W_p   = (const float*)d_in[20];
  const float* b_p   = (const float*)d_in[21];
  float* out = (float*)d_out;

  float* ws    = (float*)d_ws;
  float* vbuf  = ws;
  float* webuf = vbuf  + (size_t)NROWS*DS;
  float* ebuf  = webuf + (size_t)NROWS*DS;
  float* abuf  = ebuf  + (size_t)NROWS*DS;
  float* gin   = vbuf;                            // overlay (vbuf..abuf dead)
  float* X2    = abuf  + (size_t)NROWS*DS;        // [reads|k]
  float* wbuf  = X2    + (size_t)NROWS*512;
  float* fbuf  = wbuf  + (size_t)NROWS*SM;
  short* hhist = (short*)fbuf;                    // overlays fbuf (dead)
  unsigned long long* xbuf = (unsigned long long*)(fbuf + (size_t)NROWS*DS); // 64KB fresh

  k_gather_attn<<<NROWS/4, 256, 0, stream>>>(q, r, k_emb, x_emb, Mk, X2, vbuf, wbuf);
  k_gemm_bf16<0><<<dim3(NROWS/64, 4), 256, 0, stream>>>(X2+DS, 512, DS, vbuf, DS, DS, W_a, b_a, nullptr, webuf, DS);
  k_gemm_bf16<1><<<dim3(NROWS/64, 4), 256, 0, stream>>>(webuf, DS, DS, webuf, DS, 0, W_e,   b_e,   nullptr, ebuf, DS);
  k_gemm_bf16<2><<<dim3(NROWS/64, 4), 256, 0, stream>>>(webuf, DS, DS, webuf, DS, 0, W_add, b_add, nullptr, abuf, DS);
  k_scan<<<BS, DS, 0, stream>>>(wbuf, ebuf, abuf, Mv0, X2);
  k_gemm_bf16<2><<<dim3(NROWS/64, 4), 256, 0, stream>>>(X2, 512, DS, X2+DS, 512, DS, W_f, b_f, nullptr, fbuf, DS);
  k_gemm_bf16<0><<<dim3(NROWS/64, 16), 256, 0, stream>>>(fbuf, DS, DS, fbuf, DS, 0, W_ih, b_ih, b_hh, gin, 1024);
  {
    const float* gin_c = gin;
    void* args[] = { (void*)&gin_c, (void*)&W_hh, (void*)&hx, (void*)&cx,
                     (void*)&hhist, (void*)&xbuf };
    hipLaunchCooperativeKernel((void*)k_lstm2, dim3(LBLK), dim3(512), args, 0, stream);
  }
  k_pout<<<NROWS/4, 256, 0, stream>>>(hhist, W_p, b_p, out);
}